// Round 5
// baseline (390.651 us; speedup 1.0000x reference)
//
#include <hip/hip_runtime.h>

// GCN: 4 layers, N=50000, E=640000, d=128 (last 128->40).
// R5: UN-fused (R4 fusion cut TLP). Key idea: feature-dim chunking for
// XCD-L2-resident gathers. h stored chunk-major [8][N][16] floats; agg blocks
// pinned to XCDs via blockIdx&7 (round-robin dispatch heuristic) so each
// XCD's 4MB L2 holds its 3.2MB column slice; random gather becomes L2-local.

#define DIM 128
#define NCHUNK 8
#define CCOLS 16          // DIM / NCHUNK
#define CHUNK 1024        // scan chunk

__global__ void deg_kernel(const int* __restrict__ dst, int* __restrict__ deg, int E) {
    int i = blockIdx.x * blockDim.x + threadIdx.x;
    if (i < E) atomicAdd(&deg[dst[i]], 1);
}

// Phase A: per-chunk sums of deg; also computes nrm = rsqrt(max(deg,1)).
__global__ __launch_bounds__(256) void scanA_kernel(
        const int* __restrict__ deg, float* __restrict__ nrm,
        int* __restrict__ bsum, int n) {
    int b = blockIdx.x, t = threadIdx.x;
    int base = b * CHUNK + t * 4;
    int s = 0;
    if (base + 3 < n) {
        int4 d = *(const int4*)&deg[base];
        s = d.x + d.y + d.z + d.w;
        float4 r;
        r.x = rsqrtf(fmaxf((float)d.x, 1.0f));
        r.y = rsqrtf(fmaxf((float)d.y, 1.0f));
        r.z = rsqrtf(fmaxf((float)d.z, 1.0f));
        r.w = rsqrtf(fmaxf((float)d.w, 1.0f));
        *(float4*)&nrm[base] = r;
    } else {
        for (int j = 0; j < 4; ++j) {
            int idx = base + j;
            if (idx < n) {
                int d = deg[idx];
                s += d;
                nrm[idx] = rsqrtf(fmaxf((float)d, 1.0f));
            }
        }
    }
    for (int o = 32; o; o >>= 1) s += __shfl_down(s, o, 64);
    __shared__ int ws[4];
    if ((t & 63) == 0) ws[t >> 6] = s;
    __syncthreads();
    if (t == 0) bsum[b] = ws[0] + ws[1] + ws[2] + ws[3];
}

// Phase B: exclusive scan of bsum[G] in one wave (G <= 64); writes off[n]=total.
__global__ void scanB_kernel(int* __restrict__ bsum, int* __restrict__ off,
                             int G, int n) {
    int t = threadIdx.x;
    int orig = (t < G) ? bsum[t] : 0;
    int v = orig;
    for (int o = 1; o < 64; o <<= 1) {
        int u = __shfl_up(v, o, 64);
        if (t >= o) v += u;
    }
    if (t < G) bsum[t] = v - orig;
    if (t == G - 1) off[n] = v;
}

// Phase C: off[i] = bsum[chunk] + prefix within chunk. int4 coalesced.
__global__ __launch_bounds__(256) void scanC_kernel(
        const int* __restrict__ deg, const int* __restrict__ bsum,
        int* __restrict__ off, int n) {
    int b = blockIdx.x, t = threadIdx.x;
    int base = b * CHUNK + t * 4;
    int d0 = 0, d1 = 0, d2 = 0, d3 = 0;
    if (base + 3 < n) {
        int4 d = *(const int4*)&deg[base];
        d0 = d.x; d1 = d.y; d2 = d.z; d3 = d.w;
    } else {
        if (base     < n) d0 = deg[base];
        if (base + 1 < n) d1 = deg[base + 1];
        if (base + 2 < n) d2 = deg[base + 2];
    }
    int tot = d0 + d1 + d2 + d3;
    int v = tot;
    for (int o = 1; o < 64; o <<= 1) {
        int u = __shfl_up(v, o, 64);
        if ((t & 63) >= o) v += u;
    }
    __shared__ int wsum[4];
    if ((t & 63) == 63) wsum[t >> 6] = v;
    __syncthreads();
    int wbase = 0;
    for (int w = 0; w < (t >> 6); ++w) wbase += wsum[w];
    int p = bsum[b] + wbase + (v - tot);
    if (base + 3 < n) {
        int4 o4 = make_int4(p, p + d0, p + d0 + d1, p + d0 + d1 + d2);
        *(int4*)&off[base] = o4;
    } else {
        if (base     < n) off[base]     = p;
        if (base + 1 < n) off[base + 1] = p + d0;
        if (base + 2 < n) off[base + 2] = p + d0 + d1;
    }
}

__global__ void fill_kernel(const int* __restrict__ src, const int* __restrict__ dst,
                            const int* __restrict__ off, int* __restrict__ cur,
                            int* __restrict__ csr, int E) {
    int i = blockIdx.x * blockDim.x + threadIdx.x;
    if (i < E) {
        int d = dst[i];
        int p = atomicAdd(&cur[d], 1);
        csr[off[d] + p] = src[i];
    }
}

// features (row-major) -> chunked [8][N][16] with nrm[row] prescale.
__global__ void scale_kernel(const float* __restrict__ f, const float* __restrict__ nrm,
                             float* __restrict__ out, int N) {
    int i = blockIdx.x * blockDim.x + threadIdx.x;
    if (i < N * 32) {
        int r = i >> 5, c4 = i & 31;
        float s = nrm[r];
        float4 v = ((const float4*)f)[i];
        v.x *= s; v.y *= s; v.z *= s; v.w *= s;
        *(float4*)&out[((size_t)(c4 >> 2) * N + r) * CCOLS + (c4 & 3) * 4] = v;
    }
}

// Chunked aggregation: block handles chunk (blockIdx&7) x 16 nodes.
// Per wave: 4 nodes (quarter-wave each). Quarter: 4 edge-slots x 4 col-lanes.
// out_c[node] = nrm[node] * sum_{s in in(node)} hin_c[s]  (hin pre-scaled).
__global__ __launch_bounds__(256) void aggc_kernel(
        const float* __restrict__ hin, const float* __restrict__ nrm,
        const int* __restrict__ off, const int* __restrict__ csr,
        float* __restrict__ out, int N) {
    int bid = blockIdx.x;
    int chunk = bid & 7;
    int nb = bid >> 3;
    int t = threadIdx.x;
    int lane = t & 63, wv = t >> 6;
    int q   = lane >> 4;          // node within wave
    int sg  = (lane >> 2) & 3;    // edge slot
    int pos = lane & 3;           // col quad (float4)
    int node = nb * 16 + wv * 4 + q;
    if (node >= N) return;
    const float* Hc = hin + (size_t)chunk * N * CCOLS;
    float*       Oc = out + (size_t)chunk * N * CCOLS;
    int b = off[node], e = off[node + 1];
    float4 acc = make_float4(0.f, 0.f, 0.f, 0.f);
    for (int j = b + sg; j < e; j += 4) {
        int s = csr[j];
        float4 v = *(const float4*)&Hc[(size_t)s * CCOLS + pos * 4];
        acc.x += v.x; acc.y += v.y; acc.z += v.z; acc.w += v.w;
    }
    acc.x += __shfl_xor(acc.x, 4, 64); acc.y += __shfl_xor(acc.y, 4, 64);
    acc.z += __shfl_xor(acc.z, 4, 64); acc.w += __shfl_xor(acc.w, 4, 64);
    acc.x += __shfl_xor(acc.x, 8, 64); acc.y += __shfl_xor(acc.y, 8, 64);
    acc.z += __shfl_xor(acc.z, 8, 64); acc.w += __shfl_xor(acc.w, 8, 64);
    if (sg == 0) {
        float s = nrm[node];
        acc.x *= s; acc.y *= s; acc.z *= s; acc.w *= s;
        *(float4*)&Oc[(size_t)node * CCOLS + pos * 4] = acc;
    }
}

// GEMM 128x128 on chunked A: C = relu(A@W) * nrm[row], written chunked.
__global__ __launch_bounds__(256) void gemmc_kernel(
        const float* __restrict__ A, const float* __restrict__ W,
        const float* __restrict__ nrm, float* __restrict__ out, int n) {
    __shared__ float As[64 * DIM];
    int t = threadIdx.x;
    int row0 = blockIdx.x * 64;

    for (int qq = t; qq < 64 * 32; qq += 256) {
        int r = qq >> 5, c4 = qq & 31;
        int row = row0 + r;
        float4 v = make_float4(0.f, 0.f, 0.f, 0.f);
        if (row < n)
            v = *(const float4*)&A[((size_t)(c4 >> 2) * n + row) * CCOLS + (c4 & 3) * 4];
        *(float4*)&As[r * DIM + c4 * 4] = v;
    }
    __syncthreads();

    int tc = t & 31, tr = t >> 5;
    float acc[8][4];
#pragma unroll
    for (int i = 0; i < 8; ++i)
#pragma unroll
        for (int j = 0; j < 4; ++j) acc[i][j] = 0.f;

    for (int k4 = 0; k4 < 32; ++k4) {
        float w[4][4];
#pragma unroll
        for (int dk = 0; dk < 4; ++dk) {
            float4 wv4 = *(const float4*)&W[(size_t)(k4 * 4 + dk) * DIM + tc * 4];
            w[dk][0] = wv4.x; w[dk][1] = wv4.y; w[dk][2] = wv4.z; w[dk][3] = wv4.w;
        }
#pragma unroll
        for (int i = 0; i < 8; ++i) {
            float4 a = *(const float4*)&As[(tr * 8 + i) * DIM + k4 * 4];
            float av[4] = {a.x, a.y, a.z, a.w};
#pragma unroll
            for (int dk = 0; dk < 4; ++dk)
#pragma unroll
                for (int j = 0; j < 4; ++j)
                    acc[i][j] += av[dk] * w[dk][j];
        }
    }

#pragma unroll
    for (int i = 0; i < 8; ++i) {
        int row = row0 + tr * 8 + i;
        if (row >= n) continue;
        float s = nrm[row];
        float4 v = make_float4(acc[i][0], acc[i][1], acc[i][2], acc[i][3]);
        v.x = fmaxf(v.x, 0.f) * s; v.y = fmaxf(v.y, 0.f) * s;
        v.z = fmaxf(v.z, 0.f) * s; v.w = fmaxf(v.w, 0.f) * s;
        *(float4*)&out[((size_t)(tc >> 2) * n + row) * CCOLS + (tc & 3) * 4] = v;
    }
}

// Layer-3 GEMM: chunked A (128) -> row-major out (outw<=64), no relu/scale.
__global__ __launch_bounds__(256) void gemm3_kernel(
        const float* __restrict__ A, const float* __restrict__ W,
        float* __restrict__ out, int n, int outw) {
    __shared__ float As[64 * DIM];
    int t = threadIdx.x;
    int row0 = blockIdx.x * 64;
    for (int qq = t; qq < 64 * 32; qq += 256) {
        int r = qq >> 5, c4 = qq & 31;
        int row = row0 + r;
        float4 v = make_float4(0.f, 0.f, 0.f, 0.f);
        if (row < n)
            v = *(const float4*)&A[((size_t)(c4 >> 2) * n + row) * CCOLS + (c4 & 3) * 4];
        *(float4*)&As[r * DIM + c4 * 4] = v;
    }
    __syncthreads();

    int tc = t & 31, tr = t >> 5;
    float acc[8][2];
#pragma unroll
    for (int i = 0; i < 8; ++i) { acc[i][0] = 0.f; acc[i][1] = 0.f; }

    for (int k4 = 0; k4 < 32; ++k4) {
        float w[4][2];
#pragma unroll
        for (int dk = 0; dk < 4; ++dk) {
            int k = k4 * 4 + dk;
            int c0 = tc * 2, c1 = c0 + 1;
            w[dk][0] = (c0 < outw) ? W[(size_t)k * outw + c0] : 0.f;
            w[dk][1] = (c1 < outw) ? W[(size_t)k * outw + c1] : 0.f;
        }
#pragma unroll
        for (int i = 0; i < 8; ++i) {
            float4 a = *(const float4*)&As[(tr * 8 + i) * DIM + k4 * 4];
            float av[4] = {a.x, a.y, a.z, a.w};
#pragma unroll
            for (int dk = 0; dk < 4; ++dk) {
                acc[i][0] += av[dk] * w[dk][0];
                acc[i][1] += av[dk] * w[dk][1];
            }
        }
    }

#pragma unroll
    for (int i = 0; i < 8; ++i) {
        int row = row0 + tr * 8 + i;
        if (row >= n) continue;
#pragma unroll
        for (int j = 0; j < 2; ++j) {
            int cc = tc * 2 + j;
            if (cc < outw) out[(size_t)row * outw + cc] = acc[i][j];
        }
    }
}

// Final aggregation, 40-dim row-major. float2 x 20 lanes per half-wave;
// halves take even/odd edges, cross-half shfl reduce.
__global__ __launch_bounds__(256) void agg40_kernel(
        const float* __restrict__ hin, const float* __restrict__ nrm,
        const int* __restrict__ off, const int* __restrict__ csr,
        float* __restrict__ out, int N) {
    int lane = threadIdx.x & 63;
    int node = blockIdx.x * 4 + (threadIdx.x >> 6);
    if (node >= N) return;
    int half = lane >> 5, c2 = lane & 31;
    int b = off[node], e = off[node + 1];
    float x0=0, y0=0, x1=0, y1=0, x2=0, y2=0, x3=0, y3=0;
    if (c2 < 20) {
        int j = b + half;
        for (; j + 6 < e; j += 8) {
            int s0 = csr[j], s1 = csr[j+2], s2 = csr[j+4], s3 = csr[j+6];
            float2 v0 = *(const float2*)&hin[(size_t)s0 * 40 + c2 * 2];
            float2 v1 = *(const float2*)&hin[(size_t)s1 * 40 + c2 * 2];
            float2 v2 = *(const float2*)&hin[(size_t)s2 * 40 + c2 * 2];
            float2 v3 = *(const float2*)&hin[(size_t)s3 * 40 + c2 * 2];
            x0+=v0.x; y0+=v0.y; x1+=v1.x; y1+=v1.y;
            x2+=v2.x; y2+=v2.y; x3+=v3.x; y3+=v3.y;
        }
        for (; j < e; j += 2) {
            float2 v = *(const float2*)&hin[(size_t)csr[j] * 40 + c2 * 2];
            x0+=v.x; y0+=v.y;
        }
    }
    float rx = (x0+x1) + (x2+x3), ry = (y0+y1) + (y2+y3);
    rx += __shfl_xor(rx, 32, 64);
    ry += __shfl_xor(ry, 32, 64);
    if (half == 0 && c2 < 20) {
        float s = nrm[node];
        *(float2*)&out[(size_t)node * 40 + c2 * 2] = make_float2(rx * s, ry * s);
    }
}

extern "C" void kernel_launch(void* const* d_in, const int* in_sizes, int n_in,
                              void* d_out, int out_size, void* d_ws, size_t ws_size,
                              hipStream_t stream) {
    const float* features = (const float*)d_in[0];
    const int*   edges    = (const int*)d_in[1];
    const float* W0       = (const float*)d_in[2];
    const float* W1       = (const float*)d_in[3];
    const float* W2       = (const float*)d_in[4];
    const float* W3       = (const float*)d_in[5];

    const int N = in_sizes[0] / DIM;       // 50000
    const int E = in_sizes[1] / 2;         // 640000
    const int DOUT = out_size / N;         // 40
    const int* src = edges;
    const int* dst = edges + E;

    char* p = (char*)d_ws;
    float* bufA = (float*)p;  p += (size_t)N * DIM * 4;   // chunked [8][N][16]
    float* bufB = (float*)p;  p += (size_t)N * DIM * 4;   // chunked [8][N][16]
    float* nrm  = (float*)p;  p += (size_t)N * 4;
    int*   deg  = (int*)p;    p += (size_t)N * 4;
    int*   cur  = (int*)p;    p += (size_t)N * 4;   // adjacent to deg -> one memset
    int*   off  = (int*)p;    p += (size_t)(N + 1) * 4;
    int*   bsum = (int*)p;    p += 64 * 4;
    int*   csr  = (int*)p;    p += (size_t)E * 4;
    (void)ws_size; (void)n_in;

    hipMemsetAsync(deg, 0, (size_t)N * 2 * sizeof(int), stream);  // deg + cur

    int eb = (E + 255) / 256;
    int G  = (N + CHUNK - 1) / CHUNK;      // 49
    deg_kernel <<<eb, 256, 0, stream>>>(dst, deg, E);
    scanA_kernel<<<G, 256, 0, stream>>>(deg, nrm, bsum, N);
    scanB_kernel<<<1, 64, 0, stream>>>(bsum, off, G, N);
    scanC_kernel<<<G, 256, 0, stream>>>(deg, bsum, off, N);
    fill_kernel<<<eb, 256, 0, stream>>>(src, dst, off, cur, csr, E);

    // features -> chunked + prescale
    scale_kernel<<<(N * 32 + 255) / 256, 256, 0, stream>>>(features, nrm, bufA, N);

    int gb = (N + 63) / 64;
    int acb = NCHUNK * ((N + 15) / 16);    // 8 * 3125 = 25000, chunk = bid&7
    int ab = (N + 3) / 4;

    aggc_kernel <<<acb, 256, 0, stream>>>(bufA, nrm, off, csr, bufB, N);
    gemmc_kernel<<<gb, 256, 0, stream>>>(bufB, W0, nrm, bufA, N);

    aggc_kernel <<<acb, 256, 0, stream>>>(bufA, nrm, off, csr, bufB, N);
    gemmc_kernel<<<gb, 256, 0, stream>>>(bufB, W1, nrm, bufA, N);

    aggc_kernel <<<acb, 256, 0, stream>>>(bufA, nrm, off, csr, bufB, N);
    gemmc_kernel<<<gb, 256, 0, stream>>>(bufB, W2, nrm, bufA, N);

    // layer 3: GEMM first (128->40, row-major out), then aggregate 40-dim
    gemm3_kernel<<<gb, 256, 0, stream>>>(bufA, W3, bufB, N, DOUT);
    agg40_kernel<<<ab, 256, 0, stream>>>(bufB, nrm, off, csr, (float*)d_out, N);
}

// Round 6
// 377.543 us; speedup vs baseline: 1.0347x; 1.0347x over previous
//
#include <hip/hip_runtime.h>

// GCN: 4 layers, N=50000, E=640000, d=128 (last 128->40).
// R6: row-major gather restored (R5 chunking made it L2-resident but slower
// -> not BW-bound; it's concurrency-bound). agg = one wave/node, float4
// half-row, 4-deep ILP per half = 8 edge-rows (4KB) in flight per wave.
// Last layer: GEMM pads out to [N][64] so final agg is float4 quarter-row.

#define DIM 128
#define CHUNK 1024        // scan chunk

__global__ void deg_kernel(const int* __restrict__ dst, int* __restrict__ deg, int E) {
    int i = blockIdx.x * blockDim.x + threadIdx.x;
    if (i < E) atomicAdd(&deg[dst[i]], 1);
}

// Phase A: per-chunk sums of deg; also computes nrm = rsqrt(max(deg,1)).
__global__ __launch_bounds__(256) void scanA_kernel(
        const int* __restrict__ deg, float* __restrict__ nrm,
        int* __restrict__ bsum, int n) {
    int b = blockIdx.x, t = threadIdx.x;
    int base = b * CHUNK + t * 4;
    int s = 0;
    if (base + 3 < n) {
        int4 d = *(const int4*)&deg[base];
        s = d.x + d.y + d.z + d.w;
        float4 r;
        r.x = rsqrtf(fmaxf((float)d.x, 1.0f));
        r.y = rsqrtf(fmaxf((float)d.y, 1.0f));
        r.z = rsqrtf(fmaxf((float)d.z, 1.0f));
        r.w = rsqrtf(fmaxf((float)d.w, 1.0f));
        *(float4*)&nrm[base] = r;
    } else {
        for (int j = 0; j < 4; ++j) {
            int idx = base + j;
            if (idx < n) {
                int d = deg[idx];
                s += d;
                nrm[idx] = rsqrtf(fmaxf((float)d, 1.0f));
            }
        }
    }
    for (int o = 32; o; o >>= 1) s += __shfl_down(s, o, 64);
    __shared__ int ws[4];
    if ((t & 63) == 0) ws[t >> 6] = s;
    __syncthreads();
    if (t == 0) bsum[b] = ws[0] + ws[1] + ws[2] + ws[3];
}

// Phase B: exclusive scan of bsum[G] in one wave (G <= 64); writes off[n]=total.
__global__ void scanB_kernel(int* __restrict__ bsum, int* __restrict__ off,
                             int G, int n) {
    int t = threadIdx.x;
    int orig = (t < G) ? bsum[t] : 0;
    int v = orig;
    for (int o = 1; o < 64; o <<= 1) {
        int u = __shfl_up(v, o, 64);
        if (t >= o) v += u;
    }
    if (t < G) bsum[t] = v - orig;
    if (t == G - 1) off[n] = v;
}

// Phase C: off[i] = bsum[chunk] + prefix within chunk. int4 coalesced.
__global__ __launch_bounds__(256) void scanC_kernel(
        const int* __restrict__ deg, const int* __restrict__ bsum,
        int* __restrict__ off, int n) {
    int b = blockIdx.x, t = threadIdx.x;
    int base = b * CHUNK + t * 4;
    int d0 = 0, d1 = 0, d2 = 0, d3 = 0;
    if (base + 3 < n) {
        int4 d = *(const int4*)&deg[base];
        d0 = d.x; d1 = d.y; d2 = d.z; d3 = d.w;
    } else {
        if (base     < n) d0 = deg[base];
        if (base + 1 < n) d1 = deg[base + 1];
        if (base + 2 < n) d2 = deg[base + 2];
    }
    int tot = d0 + d1 + d2 + d3;
    int v = tot;
    for (int o = 1; o < 64; o <<= 1) {
        int u = __shfl_up(v, o, 64);
        if ((t & 63) >= o) v += u;
    }
    __shared__ int wsum[4];
    if ((t & 63) == 63) wsum[t >> 6] = v;
    __syncthreads();
    int wbase = 0;
    for (int w = 0; w < (t >> 6); ++w) wbase += wsum[w];
    int p = bsum[b] + wbase + (v - tot);
    if (base + 3 < n) {
        int4 o4 = make_int4(p, p + d0, p + d0 + d1, p + d0 + d1 + d2);
        *(int4*)&off[base] = o4;
    } else {
        if (base     < n) off[base]     = p;
        if (base + 1 < n) off[base + 1] = p + d0;
        if (base + 2 < n) off[base + 2] = p + d0 + d1;
    }
}

__global__ void fill_kernel(const int* __restrict__ src, const int* __restrict__ dst,
                            const int* __restrict__ off, int* __restrict__ cur,
                            int* __restrict__ csr, int E) {
    int i = blockIdx.x * blockDim.x + threadIdx.x;
    if (i < E) {
        int d = dst[i];
        int p = atomicAdd(&cur[d], 1);
        csr[off[d] + p] = src[i];
    }
}

// bufA = features * nrm[row]  (row-major)
__global__ void scale_kernel(const float* __restrict__ f, const float* __restrict__ nrm,
                             float* __restrict__ out, int n4) {
    int i = blockIdx.x * blockDim.x + threadIdx.x;
    if (i < n4) {
        int r = i >> 5;
        float s = nrm[r];
        float4 v = ((const float4*)f)[i];
        v.x *= s; v.y *= s; v.z *= s; v.w *= s;
        ((float4*)out)[i] = v;
    }
}

// One wave per node, 128-dim rows. Lane holds float4 at c=(lane&31)*4; the 32
// lanes of a half cover the full 512B row. Halves take even/odd edges, 4-deep
// ILP each -> 8 edge-rows (4KB) outstanding per wave. Cross-half shfl reduce.
__global__ __launch_bounds__(256) void agg_kernel(
        const float* __restrict__ hin, const float* __restrict__ nrm,
        const int* __restrict__ off, const int* __restrict__ csr,
        float* __restrict__ out, int N) {
    int lane = threadIdx.x & 63;
    int node = blockIdx.x * 4 + (threadIdx.x >> 6);
    if (node >= N) return;
    int half = lane >> 5, c = (lane & 31) * 4;
    int b = off[node], e = off[node + 1];
    float4 a0 = make_float4(0,0,0,0), a1 = a0, a2 = a0, a3 = a0;
    int j = b + half;
    for (; j + 6 < e; j += 8) {
        int s0 = csr[j], s1 = csr[j+2], s2 = csr[j+4], s3 = csr[j+6];
        float4 v0 = *(const float4*)&hin[(size_t)s0 * DIM + c];
        float4 v1 = *(const float4*)&hin[(size_t)s1 * DIM + c];
        float4 v2 = *(const float4*)&hin[(size_t)s2 * DIM + c];
        float4 v3 = *(const float4*)&hin[(size_t)s3 * DIM + c];
        a0.x+=v0.x; a0.y+=v0.y; a0.z+=v0.z; a0.w+=v0.w;
        a1.x+=v1.x; a1.y+=v1.y; a1.z+=v1.z; a1.w+=v1.w;
        a2.x+=v2.x; a2.y+=v2.y; a2.z+=v2.z; a2.w+=v2.w;
        a3.x+=v3.x; a3.y+=v3.y; a3.z+=v3.z; a3.w+=v3.w;
    }
    for (; j < e; j += 2) {
        float4 v = *(const float4*)&hin[(size_t)csr[j] * DIM + c];
        a0.x+=v.x; a0.y+=v.y; a0.z+=v.z; a0.w+=v.w;
    }
    float4 r;
    r.x = (a0.x+a1.x) + (a2.x+a3.x);
    r.y = (a0.y+a1.y) + (a2.y+a3.y);
    r.z = (a0.z+a1.z) + (a2.z+a3.z);
    r.w = (a0.w+a1.w) + (a2.w+a3.w);
    r.x += __shfl_xor(r.x, 32, 64);
    r.y += __shfl_xor(r.y, 32, 64);
    r.z += __shfl_xor(r.z, 32, 64);
    r.w += __shfl_xor(r.w, 32, 64);
    if (half == 0) {
        float s = nrm[node];
        r.x *= s; r.y *= s; r.z *= s; r.w *= s;
        *(float4*)&out[(size_t)node * DIM + c] = r;
    }
}

// C[64 x 128] = A[64 x 128] @ W[128 x 128]; A-tile in LDS (32KB, broadcast
// reads), W streamed from L2. Epilogue: relu + nrm[row] prescale.
__global__ __launch_bounds__(256) void gemm_kernel(
        const float* __restrict__ A, const float* __restrict__ W,
        const float* __restrict__ nrm, float* __restrict__ out, int n) {
    __shared__ float As[64 * DIM];
    int t = threadIdx.x;
    int row0 = blockIdx.x * 64;

    for (int q = t; q < 64 * 32; q += 256) {
        int r = q >> 5, c4 = q & 31;
        int row = row0 + r;
        float4 v = (row < n) ? *(const float4*)&A[(size_t)row * DIM + c4 * 4]
                             : make_float4(0.f, 0.f, 0.f, 0.f);
        *(float4*)&As[r * DIM + c4 * 4] = v;
    }
    __syncthreads();

    int tc = t & 31, tr = t >> 5;
    float acc[8][4];
#pragma unroll
    for (int i = 0; i < 8; ++i)
#pragma unroll
        for (int j = 0; j < 4; ++j) acc[i][j] = 0.f;

    for (int k4 = 0; k4 < 32; ++k4) {
        float w[4][4];
#pragma unroll
        for (int dk = 0; dk < 4; ++dk) {
            float4 wv4 = *(const float4*)&W[(size_t)(k4 * 4 + dk) * DIM + tc * 4];
            w[dk][0] = wv4.x; w[dk][1] = wv4.y; w[dk][2] = wv4.z; w[dk][3] = wv4.w;
        }
#pragma unroll
        for (int i = 0; i < 8; ++i) {
            float4 a = *(const float4*)&As[(tr * 8 + i) * DIM + k4 * 4];
            float av[4] = {a.x, a.y, a.z, a.w};
#pragma unroll
            for (int dk = 0; dk < 4; ++dk)
#pragma unroll
                for (int j = 0; j < 4; ++j)
                    acc[i][j] += av[dk] * w[dk][j];
        }
    }

#pragma unroll
    for (int i = 0; i < 8; ++i) {
        int row = row0 + tr * 8 + i;
        if (row >= n) continue;
        float s = nrm[row];
        float4 v = make_float4(acc[i][0], acc[i][1], acc[i][2], acc[i][3]);
        v.x = fmaxf(v.x, 0.f) * s; v.y = fmaxf(v.y, 0.f) * s;
        v.z = fmaxf(v.z, 0.f) * s; v.w = fmaxf(v.w, 0.f) * s;
        *(float4*)&out[(size_t)row * DIM + tc * 4] = v;
    }
}

// Layer-3 GEMM: A[64x128] @ W[128 x outw] -> out zero-PADDED to [n][64].
__global__ __launch_bounds__(256) void gemm3_kernel(
        const float* __restrict__ A, const float* __restrict__ W,
        float* __restrict__ out, int n, int outw) {
    __shared__ float As[64 * DIM];
    int t = threadIdx.x;
    int row0 = blockIdx.x * 64;
    for (int q = t; q < 64 * 32; q += 256) {
        int r = q >> 5, c4 = q & 31;
        int row = row0 + r;
        float4 v = (row < n) ? *(const float4*)&A[(size_t)row * DIM + c4 * 4]
                             : make_float4(0.f, 0.f, 0.f, 0.f);
        *(float4*)&As[r * DIM + c4 * 4] = v;
    }
    __syncthreads();

    int tc = t & 31, tr = t >> 5;
    float acc[8][2];
#pragma unroll
    for (int i = 0; i < 8; ++i) { acc[i][0] = 0.f; acc[i][1] = 0.f; }

    for (int k4 = 0; k4 < 32; ++k4) {
        float w[4][2];
#pragma unroll
        for (int dk = 0; dk < 4; ++dk) {
            int k = k4 * 4 + dk;
            int c0 = tc * 2, c1 = c0 + 1;
            w[dk][0] = (c0 < outw) ? W[(size_t)k * outw + c0] : 0.f;
            w[dk][1] = (c1 < outw) ? W[(size_t)k * outw + c1] : 0.f;
        }
#pragma unroll
        for (int i = 0; i < 8; ++i) {
            float4 a = *(const float4*)&As[(tr * 8 + i) * DIM + k4 * 4];
            float av[4] = {a.x, a.y, a.z, a.w};
#pragma unroll
            for (int dk = 0; dk < 4; ++dk) {
                acc[i][0] += av[dk] * w[dk][0];
                acc[i][1] += av[dk] * w[dk][1];
            }
        }
    }

#pragma unroll
    for (int i = 0; i < 8; ++i) {
        int row = row0 + tr * 8 + i;
        if (row >= n) continue;
        // always write (zero-pad cols >= outw) so agg64 can read [row][64]
        out[(size_t)row * 64 + tc * 2]     = acc[i][0];
        out[(size_t)row * 64 + tc * 2 + 1] = acc[i][1];
    }
}

// Final agg over padded [N][64] rows -> d_out [N][40].
// Half-wave per node: pos = lane&15 (float4 covers 64 floats), sg = bit4
// (even/odd edges), 4-deep ILP -> 8 edge-rows per node in flight.
__global__ __launch_bounds__(256) void agg64_kernel(
        const float* __restrict__ hin, const float* __restrict__ nrm,
        const int* __restrict__ off, const int* __restrict__ csr,
        float* __restrict__ out, int N) {
    int t = threadIdx.x;
    int lane = t & 63, wv = t >> 6;
    int node = blockIdx.x * 8 + wv * 2 + (lane >> 5);
    if (node >= N) return;
    int pos = lane & 15, sg = (lane >> 4) & 1;
    int b = off[node], e = off[node + 1];
    float4 a0 = make_float4(0,0,0,0), a1 = a0, a2 = a0, a3 = a0;
    int j = b + sg;
    for (; j + 6 < e; j += 8) {
        int s0 = csr[j], s1 = csr[j+2], s2 = csr[j+4], s3 = csr[j+6];
        float4 v0 = *(const float4*)&hin[(size_t)s0 * 64 + pos * 4];
        float4 v1 = *(const float4*)&hin[(size_t)s1 * 64 + pos * 4];
        float4 v2 = *(const float4*)&hin[(size_t)s2 * 64 + pos * 4];
        float4 v3 = *(const float4*)&hin[(size_t)s3 * 64 + pos * 4];
        a0.x+=v0.x; a0.y+=v0.y; a0.z+=v0.z; a0.w+=v0.w;
        a1.x+=v1.x; a1.y+=v1.y; a1.z+=v1.z; a1.w+=v1.w;
        a2.x+=v2.x; a2.y+=v2.y; a2.z+=v2.z; a2.w+=v2.w;
        a3.x+=v3.x; a3.y+=v3.y; a3.z+=v3.z; a3.w+=v3.w;
    }
    for (; j < e; j += 2) {
        float4 v = *(const float4*)&hin[(size_t)csr[j] * 64 + pos * 4];
        a0.x+=v.x; a0.y+=v.y; a0.z+=v.z; a0.w+=v.w;
    }
    float4 r;
    r.x = (a0.x+a1.x) + (a2.x+a3.x);
    r.y = (a0.y+a1.y) + (a2.y+a3.y);
    r.z = (a0.z+a1.z) + (a2.z+a3.z);
    r.w = (a0.w+a1.w) + (a2.w+a3.w);
    r.x += __shfl_xor(r.x, 16, 64);
    r.y += __shfl_xor(r.y, 16, 64);
    r.z += __shfl_xor(r.z, 16, 64);
    r.w += __shfl_xor(r.w, 16, 64);
    if (sg == 0 && pos < 10) {          // cols 0..39
        float s = nrm[node];
        r.x *= s; r.y *= s; r.z *= s; r.w *= s;
        *(float4*)&out[(size_t)node * 40 + pos * 4] = r;
    }
}

extern "C" void kernel_launch(void* const* d_in, const int* in_sizes, int n_in,
                              void* d_out, int out_size, void* d_ws, size_t ws_size,
                              hipStream_t stream) {
    const float* features = (const float*)d_in[0];
    const int*   edges    = (const int*)d_in[1];
    const float* W0       = (const float*)d_in[2];
    const float* W1       = (const float*)d_in[3];
    const float* W2       = (const float*)d_in[4];
    const float* W3       = (const float*)d_in[5];

    const int N = in_sizes[0] / DIM;       // 50000
    const int E = in_sizes[1] / 2;         // 640000
    const int DOUT = out_size / N;         // 40
    const int* src = edges;
    const int* dst = edges + E;

    char* p = (char*)d_ws;
    float* bufA = (float*)p;  p += (size_t)N * DIM * 4;
    float* bufB = (float*)p;  p += (size_t)N * DIM * 4;
    float* nrm  = (float*)p;  p += (size_t)N * 4;
    int*   deg  = (int*)p;    p += (size_t)N * 4;
    int*   cur  = (int*)p;    p += (size_t)N * 4;   // adjacent to deg -> one memset
    int*   off  = (int*)p;    p += (size_t)(N + 1) * 4;
    int*   bsum = (int*)p;    p += 64 * 4;
    int*   csr  = (int*)p;    p += (size_t)E * 4;
    (void)ws_size; (void)n_in;

    hipMemsetAsync(deg, 0, (size_t)N * 2 * sizeof(int), stream);  // deg + cur

    int eb = (E + 255) / 256;
    int G  = (N + CHUNK - 1) / CHUNK;      // 49
    deg_kernel <<<eb, 256, 0, stream>>>(dst, deg, E);
    scanA_kernel<<<G, 256, 0, stream>>>(deg, nrm, bsum, N);
    scanB_kernel<<<1, 64, 0, stream>>>(bsum, off, G, N);
    scanC_kernel<<<G, 256, 0, stream>>>(deg, bsum, off, N);
    fill_kernel<<<eb, 256, 0, stream>>>(src, dst, off, cur, csr, E);

    int n4 = N * (DIM / 4);
    scale_kernel<<<(n4 + 255) / 256, 256, 0, stream>>>(features, nrm, bufA, n4);

    int gb = (N + 63) / 64;
    int ab = (N + 3) / 4;
    agg_kernel <<<ab, 256, 0, stream>>>(bufA, nrm, off, csr, bufB, N);
    gemm_kernel<<<gb, 256, 0, stream>>>(bufB, W0, nrm, bufA, N);

    agg_kernel <<<ab, 256, 0, stream>>>(bufA, nrm, off, csr, bufB, N);
    gemm_kernel<<<gb, 256, 0, stream>>>(bufB, W1, nrm, bufA, N);

    agg_kernel <<<ab, 256, 0, stream>>>(bufA, nrm, off, csr, bufB, N);
    gemm_kernel<<<gb, 256, 0, stream>>>(bufB, W2, nrm, bufA, N);

    // layer 3: GEMM first (128->40, padded to 64 cols), then aggregate
    gemm3_kernel<<<gb, 256, 0, stream>>>(bufA, W3, bufB, N, DOUT);
    agg64_kernel<<<(N + 7) / 8, 256, 0, stream>>>(bufB, nrm, off, csr,
                                                  (float*)d_out, N);
}